// Round 1
// baseline (2665.146 us; speedup 1.0000x reference)
//
#include <hip/hip_runtime.h>
#include <hip/hip_bf16.h>

// GCN: 3x (GEMM + normalized scatter-add) + mean-pool + linear.
// D = H = 64, C = 10. All fp32.

__device__ __forceinline__ void atomAddF(float* p, float v) {
#if defined(__gfx90a__) || defined(__gfx940__) || defined(__gfx941__) || defined(__gfx942__) || defined(__gfx950__)
    unsafeAtomicAdd(p, v);   // native global_atomic_add_f32 (no CAS loop)
#else
    atomicAdd(p, v);
#endif
}

__global__ void k_deg_init(float* deg, int n) {
    int i = blockIdx.x * blockDim.x + threadIdx.x;
    if (i < n) deg[i] = 1.0f;   // self-loop contributes 1
}

__global__ void k_deg_edges(const int* __restrict__ dst, float* deg, int nE) {
    int e = blockIdx.x * blockDim.x + threadIdx.x;
    if (e < nE) atomAddF(&deg[dst[e]], 1.0f);
}

__global__ void k_dinv(float* deg, int n) {
    int i = blockIdx.x * blockDim.x + threadIdx.x;
    if (i < n) deg[i] = rsqrtf(deg[i]);   // deg >= 1 always (self-loop)
}

// out[n][h] = sum_k act(in[n][k]) * W[k][h], act = relu(v + bias) when RELU.
// Block: 256 threads handle a 64-node x 64-h tile; 4x4 register tile each.
template<bool RELU>
__global__ void k_gemm(const float* __restrict__ in, const float* __restrict__ W,
                       const float* __restrict__ bias, float* __restrict__ out, int n) {
    __shared__ float Wl[64 * 64];     // row-major [k][h]
    __shared__ float Xl[64 * 68];     // [node][k], pad 64->68 keeps <=2-way LDS aliasing
    const int t = threadIdx.x;
    const int base = blockIdx.x * 64;

    for (int idx = t; idx < 1024; idx += 256)
        ((float4*)Wl)[idx] = ((const float4*)W)[idx];

    for (int idx = t; idx < 1024; idx += 256) {
        int r = idx >> 4;
        int k4 = (idx & 15) * 4;
        int node = base + r;
        float4 v = make_float4(0.f, 0.f, 0.f, 0.f);
        if (node < n) v = *(const float4*)(in + node * 64 + k4);
        if (RELU) {
            v.x = fmaxf(v.x + bias[k4 + 0], 0.f);
            v.y = fmaxf(v.y + bias[k4 + 1], 0.f);
            v.z = fmaxf(v.z + bias[k4 + 2], 0.f);
            v.w = fmaxf(v.w + bias[k4 + 3], 0.f);
        }
        *(float4*)(Xl + r * 68 + k4) = v;
    }
    __syncthreads();

    const int h4 = (t & 15) * 4;
    const int r4 = (t >> 4) * 4;
    float4 acc[4];
#pragma unroll
    for (int j = 0; j < 4; j++) acc[j] = make_float4(0.f, 0.f, 0.f, 0.f);

    for (int k4 = 0; k4 < 64; k4 += 4) {
        float4 w0 = *(const float4*)(Wl + (k4 + 0) * 64 + h4);
        float4 w1 = *(const float4*)(Wl + (k4 + 1) * 64 + h4);
        float4 w2 = *(const float4*)(Wl + (k4 + 2) * 64 + h4);
        float4 w3 = *(const float4*)(Wl + (k4 + 3) * 64 + h4);
#pragma unroll
        for (int j = 0; j < 4; j++) {
            float4 x = *(const float4*)(Xl + (r4 + j) * 68 + k4);
            acc[j].x += x.x * w0.x + x.y * w1.x + x.z * w2.x + x.w * w3.x;
            acc[j].y += x.x * w0.y + x.y * w1.y + x.z * w2.y + x.w * w3.y;
            acc[j].z += x.x * w0.z + x.y * w1.z + x.z * w2.z + x.w * w3.z;
            acc[j].w += x.x * w0.w + x.y * w1.w + x.z * w2.w + x.w * w3.w;
        }
    }

#pragma unroll
    for (int j = 0; j < 4; j++) {
        int node = base + r4 + j;
        if (node < n) *(float4*)(out + node * 64 + h4) = acc[j];
    }
}

// One wave per edge (lane = feature). Edges [0,nE) are real, [nE,nE+nN) self-loops.
__global__ void k_aggregate(const float* __restrict__ hW, const int* __restrict__ src,
                            const int* __restrict__ dst, const float* __restrict__ dinv,
                            float* __restrict__ agg, int nE, int nN) {
    const int lane = threadIdx.x & 63;
    const int e = blockIdx.x * (blockDim.x >> 6) + (threadIdx.x >> 6);
    if (e >= nE + nN) return;
    int s, d;
    if (e < nE) { s = src[e]; d = dst[e]; }
    else        { s = e - nE; d = s; }
    float w = dinv[s] * dinv[d];
    atomAddF(&agg[d * 64 + lane], w * hW[s * 64 + lane]);
}

// batch is sorted: run-length accumulate per 64-node chunk, flush on graph change.
__global__ void k_pool(const float* __restrict__ agg, const int* __restrict__ batch,
                       float* __restrict__ pool, float* __restrict__ cnt, int n) {
    const int lane = threadIdx.x;       // 64 threads
    const int base = blockIdx.x * 64;
    int g_cur = -1, run = 0;
    float acc = 0.f;
    for (int j = 0; j < 64; j++) {
        int node = base + j;
        if (node >= n) break;
        int g = batch[node];
        if (g != g_cur) {
            if (g_cur >= 0) {
                atomAddF(&pool[g_cur * 64 + lane], acc);
                if (lane == 0) atomAddF(&cnt[g_cur], (float)run);
            }
            g_cur = g; acc = 0.f; run = 0;
        }
        acc += agg[node * 64 + lane];
        run++;
    }
    if (g_cur >= 0) {
        atomAddF(&pool[g_cur * 64 + lane], acc);
        if (lane == 0) atomAddF(&cnt[g_cur], (float)run);
    }
}

// out[g][c] = (pool[g][:]/cnt + b3) @ Wl[:,c] + bl[c]
__global__ void k_final(const float* __restrict__ pool, const float* __restrict__ cnt,
                        const float* __restrict__ b3, const float* __restrict__ Wl,
                        const float* __restrict__ bl, float* __restrict__ out) {
    __shared__ float s[64];
    const int g = blockIdx.x, t = threadIdx.x;
    float c = fmaxf(cnt[g], 1.0f);
    s[t] = pool[g * 64 + t] / c + b3[t];
    __syncthreads();
    if (t < 10) {
        float acc = bl[t];
#pragma unroll
        for (int k = 0; k < 64; k++) acc += s[k] * Wl[k * 10 + t];
        out[g * 10 + t] = acc;
    }
}

extern "C" void kernel_launch(void* const* d_in, const int* in_sizes, int n_in,
                              void* d_out, int out_size, void* d_ws, size_t ws_size,
                              hipStream_t stream) {
    const float* x   = (const float*)d_in[0];
    const int*   ei  = (const int*)d_in[1];
    const int*   bat = (const int*)d_in[2];
    const float* W1  = (const float*)d_in[3];
    const float* b1  = (const float*)d_in[4];
    const float* W2  = (const float*)d_in[5];
    const float* b2  = (const float*)d_in[6];
    const float* W3  = (const float*)d_in[7];
    const float* b3  = (const float*)d_in[8];
    const float* Wl  = (const float*)d_in[9];
    const float* bl  = (const float*)d_in[10];
    float* out = (float*)d_out;

    const int N_ = in_sizes[0] / 64;
    const int E_ = in_sizes[1] / 2;
    const int G_ = out_size / 10;

    float* ws   = (float*)d_ws;
    float* dinv = ws;                                   // N
    float* hW   = ws + (((size_t)N_ + 3) & ~(size_t)3); // N*64
    float* agg  = hW + (size_t)N_ * 64;                 // N*64
    float* pool = agg + (size_t)N_ * 64;                // G*64
    float* cnt  = pool + (size_t)G_ * 64;               // G

    const int* srcp = ei;
    const int* dstp = ei + E_;

    hipMemsetAsync(pool, 0, (size_t)(G_ * 64 + G_) * sizeof(float), stream);

    k_deg_init<<<(N_ + 255) / 256, 256, 0, stream>>>(dinv, N_);
    k_deg_edges<<<(E_ + 255) / 256, 256, 0, stream>>>(dstp, dinv, E_);
    k_dinv<<<(N_ + 255) / 256, 256, 0, stream>>>(dinv, N_);

    const int gemm_blocks = (N_ + 63) / 64;
    const int agg_blocks  = (E_ + N_ + 3) / 4;
    const size_t agg_bytes = (size_t)N_ * 64 * sizeof(float);

    // Layer 1
    hipMemsetAsync(agg, 0, agg_bytes, stream);
    k_gemm<false><<<gemm_blocks, 256, 0, stream>>>(x, W1, nullptr, hW, N_);
    k_aggregate<<<agg_blocks, 256, 0, stream>>>(hW, srcp, dstp, dinv, agg, E_, N_);

    // Layer 2 (relu(prev + b1) applied on load)
    k_gemm<true><<<gemm_blocks, 256, 0, stream>>>(agg, W2, b1, hW, N_);
    hipMemsetAsync(agg, 0, agg_bytes, stream);
    k_aggregate<<<agg_blocks, 256, 0, stream>>>(hW, srcp, dstp, dinv, agg, E_, N_);

    // Layer 3 (relu(prev + b2) applied on load)
    k_gemm<true><<<gemm_blocks, 256, 0, stream>>>(agg, W3, b2, hW, N_);
    hipMemsetAsync(agg, 0, agg_bytes, stream);
    k_aggregate<<<agg_blocks, 256, 0, stream>>>(hW, srcp, dstp, dinv, agg, E_, N_);

    // Pool (b3 folded into final) + classifier
    k_pool<<<(N_ + 63) / 64, 64, 0, stream>>>(agg, bat, pool, cnt, N_);
    k_final<<<G_, 64, 0, stream>>>(pool, cnt, b3, Wl, bl, out);
}

// Round 2
// 627.498 us; speedup vs baseline: 4.2473x; 4.2473x over previous
//
#include <hip/hip_runtime.h>
#include <hip/hip_bf16.h>

// GCN: CSR-based aggregation (no fp32 atomics), 3x (GEMM + gather-sum),
// mean-pool, linear. D = H = 64, C = 10. All fp32.

__device__ __forceinline__ void atomAddF(float* p, float v) {
#if defined(__gfx90a__) || defined(__gfx940__) || defined(__gfx941__) || defined(__gfx942__) || defined(__gfx950__)
    unsafeAtomicAdd(p, v);
#else
    atomicAdd(p, v);
#endif
}

// ---------------- CSR construction ----------------

__global__ void k_hist(const int* __restrict__ dst, int* __restrict__ hist, int nE) {
    int e = blockIdx.x * blockDim.x + threadIdx.x;
    if (e < nE) atomicAdd(&hist[dst[e]], 1);
}

__global__ void k_dinv(const int* __restrict__ hist, float* __restrict__ dinv, int n) {
    int i = blockIdx.x * blockDim.x + threadIdx.x;
    if (i < n) dinv[i] = rsqrtf((float)hist[i] + 1.0f);   // +1 self-loop
}

// Exclusive scan, stage 1: each block scans a 1024-element chunk (256 thr x 4).
__global__ void k_scan1(const int* __restrict__ hist, int* __restrict__ rowptr,
                        int* __restrict__ bsum, int n) {
    __shared__ int s[256];
    const int t = threadIdx.x;
    const int base = blockIdx.x * 1024 + t * 4;
    int v0 = 0, v1 = 0, v2 = 0, v3 = 0;
    if (base + 3 < n) {
        int4 v = *(const int4*)(hist + base);
        v0 = v.x; v1 = v.y; v2 = v.z; v3 = v.w;
    } else {
        if (base + 0 < n) v0 = hist[base + 0];
        if (base + 1 < n) v1 = hist[base + 1];
        if (base + 2 < n) v2 = hist[base + 2];
        if (base + 3 < n) v3 = hist[base + 3];
    }
    int tsum = v0 + v1 + v2 + v3;
    s[t] = tsum;
    __syncthreads();
    for (int off = 1; off < 256; off <<= 1) {
        int val = 0;
        if (t >= off) val = s[t - off];
        __syncthreads();
        if (t >= off) s[t] += val;
        __syncthreads();
    }
    int excl = s[t] - tsum;
    if (t == 255) bsum[blockIdx.x] = s[255];
    if (base + 0 < n) rowptr[base + 0] = excl;
    if (base + 1 < n) rowptr[base + 1] = excl + v0;
    if (base + 2 < n) rowptr[base + 2] = excl + v0 + v1;
    if (base + 3 < n) rowptr[base + 3] = excl + v0 + v1 + v2;
}

// Stage 2: single block exclusive-scans the block sums (nb <= 256).
__global__ void k_scan2(int* __restrict__ bsum, int nb) {
    __shared__ int s[256];
    const int t = threadIdx.x;
    int mine = (t < nb) ? bsum[t] : 0;
    s[t] = mine;
    __syncthreads();
    for (int off = 1; off < 256; off <<= 1) {
        int val = 0;
        if (t >= off) val = s[t - off];
        __syncthreads();
        if (t >= off) s[t] += val;
        __syncthreads();
    }
    if (t < nb) bsum[t] = s[t] - mine;
}

// Stage 3: add block offsets; also seed the scatter cursors.
__global__ void k_scan3(int* __restrict__ rowptr, const int* __restrict__ bsum,
                        int* __restrict__ cursor, int n) {
    int i = blockIdx.x * blockDim.x + threadIdx.x;
    if (i < n) {
        int v = rowptr[i] + bsum[i >> 10];
        rowptr[i] = v;
        cursor[i] = v;
    }
}

// Scatter edges into dst-grouped slots; precompute the symmetric norm weight.
__global__ void k_scatter(const int* __restrict__ src, const int* __restrict__ dst,
                          const float* __restrict__ dinv, int* __restrict__ cursor,
                          int* __restrict__ csr_s, float* __restrict__ csr_w, int nE) {
    int e = blockIdx.x * blockDim.x + threadIdx.x;
    if (e >= nE) return;
    int s0 = src[e], d0 = dst[e];
    int pos = atomicAdd(&cursor[d0], 1);
    csr_s[pos] = s0;
    csr_w[pos] = dinv[s0] * dinv[d0];
}

// ---------------- GEMM (64-wide, fp32) ----------------
// out[n][h] = sum_k act(in[n][k]) * W[k][h]; act = relu(v + bias) when RELU.
template<bool RELU>
__global__ __launch_bounds__(256)
void k_gemm(const float* __restrict__ in, const float* __restrict__ W,
            const float* __restrict__ bias, float* __restrict__ out, int n) {
    __shared__ float Wl[64 * 64];     // [k][h]
    __shared__ float Xl[64 * 68];     // [node][k], +4 pad
    const int t = threadIdx.x;
    const int base = blockIdx.x * 64;

    for (int idx = t; idx < 1024; idx += 256)
        ((float4*)Wl)[idx] = ((const float4*)W)[idx];

    for (int idx = t; idx < 1024; idx += 256) {
        int r = idx >> 4;
        int k4 = (idx & 15) * 4;
        int node = base + r;
        float4 v = make_float4(0.f, 0.f, 0.f, 0.f);
        if (node < n) v = *(const float4*)(in + node * 64 + k4);
        if (RELU) {
            v.x = fmaxf(v.x + bias[k4 + 0], 0.f);
            v.y = fmaxf(v.y + bias[k4 + 1], 0.f);
            v.z = fmaxf(v.z + bias[k4 + 2], 0.f);
            v.w = fmaxf(v.w + bias[k4 + 3], 0.f);
        }
        *(float4*)(Xl + r * 68 + k4) = v;
    }
    __syncthreads();

    const int h4 = (t & 15) * 4;
    const int r4 = (t >> 4) * 4;
    float4 acc[4];
#pragma unroll
    for (int j = 0; j < 4; j++) acc[j] = make_float4(0.f, 0.f, 0.f, 0.f);

    for (int k4 = 0; k4 < 64; k4 += 4) {
        float4 w0 = *(const float4*)(Wl + (k4 + 0) * 64 + h4);
        float4 w1 = *(const float4*)(Wl + (k4 + 1) * 64 + h4);
        float4 w2 = *(const float4*)(Wl + (k4 + 2) * 64 + h4);
        float4 w3 = *(const float4*)(Wl + (k4 + 3) * 64 + h4);
#pragma unroll
        for (int j = 0; j < 4; j++) {
            float4 x = *(const float4*)(Xl + (r4 + j) * 68 + k4);
            acc[j].x += x.x * w0.x + x.y * w1.x + x.z * w2.x + x.w * w3.x;
            acc[j].y += x.x * w0.y + x.y * w1.y + x.z * w2.y + x.w * w3.y;
            acc[j].z += x.x * w0.z + x.y * w1.z + x.z * w2.z + x.w * w3.z;
            acc[j].w += x.x * w0.w + x.y * w1.w + x.z * w2.w + x.w * w3.w;
        }
    }

#pragma unroll
    for (int j = 0; j < 4; j++) {
        int node = base + r4 + j;
        if (node < n) *(float4*)(out + node * 64 + h4) = acc[j];
    }
}

// ---------------- CSR aggregation: one wave per node, lane = feature ----------------
__global__ __launch_bounds__(256)
void k_agg_csr(const float* __restrict__ hW, const int* __restrict__ rowptr,
               const int* __restrict__ rowend, const int* __restrict__ csr_s,
               const float* __restrict__ csr_w, const float* __restrict__ dinv,
               float* __restrict__ agg, int n) {
    const int lane = threadIdx.x & 63;
    const int node = blockIdx.x * 4 + (threadIdx.x >> 6);
    if (node >= n) return;
    const int row = rowptr[node];
    const int end = rowend[node];      // cursor after scatter == row end
    const float di = dinv[node];
    float acc = di * di * hW[node * 64 + lane];   // self-loop

    for (int base = row; base < end; base += 64) {
        const int m = min(64, end - base);
        int   s_l = 0;
        float w_l = 0.f;
        if (base + lane < end) {
            s_l = csr_s[base + lane];
            w_l = csr_w[base + lane];
        }
        int j = 0;
        for (; j + 4 <= m; j += 4) {
            int   s0 = __shfl(s_l, j),     s1 = __shfl(s_l, j + 1);
            int   s2 = __shfl(s_l, j + 2), s3 = __shfl(s_l, j + 3);
            float w0 = __shfl(w_l, j),     w1 = __shfl(w_l, j + 1);
            float w2 = __shfl(w_l, j + 2), w3 = __shfl(w_l, j + 3);
            float h0 = hW[s0 * 64 + lane];
            float h1 = hW[s1 * 64 + lane];
            float h2 = hW[s2 * 64 + lane];
            float h3 = hW[s3 * 64 + lane];
            acc += w0 * h0 + w1 * h1 + w2 * h2 + w3 * h3;
        }
        for (; j < m; j++) {
            int   sj = __shfl(s_l, j);
            float wj = __shfl(w_l, j);
            acc += wj * hW[sj * 64 + lane];
        }
    }
    agg[node * 64 + lane] = acc;
}

// ---------------- pooling + classifier ----------------

__global__ void k_pool(const float* __restrict__ agg, const int* __restrict__ batch,
                       float* __restrict__ pool, float* __restrict__ cnt, int n) {
    const int lane = threadIdx.x;       // 64 threads
    const int base = blockIdx.x * 64;
    int g_cur = -1, run = 0;
    float acc = 0.f;
    for (int j = 0; j < 64; j++) {
        int node = base + j;
        if (node >= n) break;
        int g = batch[node];
        if (g != g_cur) {
            if (g_cur >= 0) {
                atomAddF(&pool[g_cur * 64 + lane], acc);
                if (lane == 0) atomAddF(&cnt[g_cur], (float)run);
            }
            g_cur = g; acc = 0.f; run = 0;
        }
        acc += agg[node * 64 + lane];
        run++;
    }
    if (g_cur >= 0) {
        atomAddF(&pool[g_cur * 64 + lane], acc);
        if (lane == 0) atomAddF(&cnt[g_cur], (float)run);
    }
}

__global__ void k_final(const float* __restrict__ pool, const float* __restrict__ cnt,
                        const float* __restrict__ b3, const float* __restrict__ Wl,
                        const float* __restrict__ bl, float* __restrict__ out) {
    __shared__ float s[64];
    const int g = blockIdx.x, t = threadIdx.x;
    float c = fmaxf(cnt[g], 1.0f);
    s[t] = pool[g * 64 + t] / c + b3[t];
    __syncthreads();
    if (t < 10) {
        float acc = bl[t];
#pragma unroll
        for (int k = 0; k < 64; k++) acc += s[k] * Wl[k * 10 + t];
        out[g * 10 + t] = acc;
    }
}

extern "C" void kernel_launch(void* const* d_in, const int* in_sizes, int n_in,
                              void* d_out, int out_size, void* d_ws, size_t ws_size,
                              hipStream_t stream) {
    const float* x   = (const float*)d_in[0];
    const int*   ei  = (const int*)d_in[1];
    const int*   bat = (const int*)d_in[2];
    const float* W1  = (const float*)d_in[3];
    const float* b1  = (const float*)d_in[4];
    const float* W2  = (const float*)d_in[5];
    const float* b2  = (const float*)d_in[6];
    const float* W3  = (const float*)d_in[7];
    const float* b3  = (const float*)d_in[8];
    const float* Wl  = (const float*)d_in[9];
    const float* bl  = (const float*)d_in[10];
    float* out = (float*)d_out;

    const int N_ = in_sizes[0] / 64;
    const int E_ = in_sizes[1] / 2;
    const int G_ = out_size / 10;

    // workspace layout (4-byte words)
    char* p = (char*)d_ws;
    float* dinv   = (float*)p; p += (size_t)N_ * 4;
    float* hW     = (float*)p; p += (size_t)N_ * 64 * 4;
    float* agg    = (float*)p; p += (size_t)N_ * 64 * 4;
    float* pool   = (float*)p; p += (size_t)G_ * 64 * 4;
    float* cnt    = (float*)p; p += (size_t)G_ * 4;
    int*   hist   = (int*)p;   p += (size_t)N_ * 4;
    int*   rowptr = (int*)p;   p += (size_t)N_ * 4;
    int*   cursor = (int*)p;   p += (size_t)N_ * 4;
    int*   bsum   = (int*)p;   p += 256 * 4;
    int*   csr_s  = (int*)p;   p += (size_t)E_ * 4;
    float* csr_w  = (float*)p; p += (size_t)E_ * 4;

    const int* srcp = ei;
    const int* dstp = ei + E_;

    hipMemsetAsync(hist, 0, (size_t)N_ * 4, stream);
    hipMemsetAsync(pool, 0, (size_t)(G_ * 64 + G_) * 4, stream);

    const int nb = (N_ + 1023) / 1024;   // 98 chunks for N=100k (<=256)

    k_hist<<<(E_ + 255) / 256, 256, 0, stream>>>(dstp, hist, E_);
    k_dinv<<<(N_ + 255) / 256, 256, 0, stream>>>(hist, dinv, N_);
    k_scan1<<<nb, 256, 0, stream>>>(hist, rowptr, bsum, N_);
    k_scan2<<<1, 256, 0, stream>>>(bsum, nb);
    k_scan3<<<(N_ + 255) / 256, 256, 0, stream>>>(rowptr, bsum, cursor, N_);
    k_scatter<<<(E_ + 255) / 256, 256, 0, stream>>>(srcp, dstp, dinv, cursor,
                                                    csr_s, csr_w, E_);

    const int gemm_blocks = (N_ + 63) / 64;
    const int agg_blocks  = (N_ + 3) / 4;

    // Layer 1
    k_gemm<false><<<gemm_blocks, 256, 0, stream>>>(x, W1, nullptr, hW, N_);
    k_agg_csr<<<agg_blocks, 256, 0, stream>>>(hW, rowptr, cursor, csr_s, csr_w,
                                              dinv, agg, N_);
    // Layer 2 (relu(prev + b1) on load)
    k_gemm<true><<<gemm_blocks, 256, 0, stream>>>(agg, W2, b1, hW, N_);
    k_agg_csr<<<agg_blocks, 256, 0, stream>>>(hW, rowptr, cursor, csr_s, csr_w,
                                              dinv, agg, N_);
    // Layer 3 (relu(prev + b2) on load)
    k_gemm<true><<<gemm_blocks, 256, 0, stream>>>(agg, W3, b2, hW, N_);
    k_agg_csr<<<agg_blocks, 256, 0, stream>>>(hW, rowptr, cursor, csr_s, csr_w,
                                              dinv, agg, N_);

    // Pool (b3 folded into final) + classifier
    k_pool<<<(N_ + 63) / 64, 64, 0, stream>>>(agg, bat, pool, cnt, N_);
    k_final<<<G_, 64, 0, stream>>>(pool, cnt, b3, Wl, bl, out);
}